// Round 1
// baseline (14.525 us; speedup 1.0000x reference)
//
#include <hip/hip_runtime.h>

// Problem constants (B, S, I, d) = (8, 32, 64, 256); L = S*I = 2048.
#define NB 8
#define L 2048
#define D 256
#define ROWV (D / 4)   // 64 float4 per row

// Kernel A: per-batch stable-compaction gather-index build.
// grid = NB blocks, 256 threads each. Each thread owns 8 consecutive mask
// entries. Block-wide exclusive scan (wave shfl scan + 4-wave combine).
// src_idx[b*L + j] = flat index l of the j-th valid token in batch b, or -1.
__global__ void build_indices(const int* __restrict__ mask, int* __restrict__ src_idx) {
    const int b = blockIdx.x;
    const int t = threadIdx.x;
    const int* m = mask + b * L;
    int* si = src_idx + b * L;

    int vals[8];
    int local = 0;
#pragma unroll
    for (int k = 0; k < 8; ++k) {
        vals[k] = (m[t * 8 + k] != 0) ? 1 : 0;
        local += vals[k];
    }
    // Initialize all destination slots to -1 (padding marker).
#pragma unroll
    for (int k = 0; k < 8; ++k) si[t * 8 + k] = -1;

    // Wave-level inclusive scan of per-thread counts.
    const int lane = t & 63;
    const int wid = t >> 6;
    int x = local;
#pragma unroll
    for (int off = 1; off < 64; off <<= 1) {
        int y = __shfl_up(x, off, 64);
        if (lane >= off) x += y;
    }
    __shared__ int wave_sums[4];
    if (lane == 63) wave_sums[wid] = x;
    __syncthreads();  // also orders the -1 inits before the scatter below

    int wbase = 0;
#pragma unroll
    for (int w = 0; w < 4; ++w)
        if (w < wid) wbase += wave_sums[w];

    int excl = wbase + x - local;  // exclusive prefix for this thread's first slot
#pragma unroll
    for (int k = 0; k < 8; ++k) {
        if (vals[k]) {
            si[excl] = t * 8 + k;
            ++excl;
        }
    }
}

// Kernel B: gather rows. One wave (64 lanes) per output row; each lane moves
// one float4 (16B). src<0 -> write zeros (padding; d_out is poisoned).
__global__ void gather_rows(const float4* __restrict__ in,
                            const int* __restrict__ src_idx,
                            float4* __restrict__ out) {
    const int row = blockIdx.x * 4 + (threadIdx.x >> 6);  // [0, NB*L)
    const int lane = threadIdx.x & 63;
    const int b = row >> 11;   // / L
    const int src = src_idx[row];

    float4 v = make_float4(0.f, 0.f, 0.f, 0.f);
    if (src >= 0) {
        v = in[(size_t)(b * L + src) * ROWV + lane];
    }
    out[(size_t)row * ROWV + lane] = v;
}

extern "C" void kernel_launch(void* const* d_in, const int* in_sizes, int n_in,
                              void* d_out, int out_size, void* d_ws, size_t ws_size,
                              hipStream_t stream) {
    const float* ffn_out = (const float*)d_in[0];
    const int* valid_mask = (const int*)d_in[1];  // bool staged as int32 (nonzero = valid)
    float* out = (float*)d_out;
    int* src_idx = (int*)d_ws;  // NB*L ints = 64 KB

    build_indices<<<NB, 256, 0, stream>>>(valid_mask, src_idx);
    gather_rows<<<NB * L / 4, 256, 0, stream>>>(
        (const float4*)ffn_out, src_idx, (float4*)out);
}